// Round 7
// baseline (134.152 us; speedup 1.0000x reference)
//
#include <hip/hip_runtime.h>
#include <math.h>

// Shapes fixed by the reference: x [B=16, C=512, N=4096] fp32.
constexpr int B  = 16;
constexpr int C  = 512;
constexpr int N  = 4096;
constexpr int CR = 128;   // C/4
constexpr int NT = 64;    // n-tile per k_main block (16 per wave)

typedef __attribute__((ext_vector_type(8))) short bf16x8;
typedef __attribute__((ext_vector_type(4))) float f32x4;
typedef __attribute__((ext_vector_type(4))) unsigned u32x4;

__device__ __forceinline__ float sigmoidf_(float v) {
    return 1.0f / (1.0f + __expf(-v));
}
// fp32 -> bf16 round-to-nearest-even (bits in low 16)
__device__ __forceinline__ unsigned f2bf(float f) {
    unsigned u = __float_as_uint(f);
    u += 0x7fffu + ((u >> 16) & 1u);
    return u >> 16;
}

// ---------------------------------------------------------------------------
// k_pre: fused  (blocks 0..2047)  pooled[b][c] = mean_n x[b][c][n]
//               (blocks 2048..2079) BN-fold w3 -> bf16 in MFMA A-FRAGMENT
//               lane order (w3f) + bias2.
// w3f layout: group g = ck*16 + kk*8 + ob ; byte(g,lane) = (g*64+lane)*16
//   content: w[ob*16+(lane&15)][ck*64+kk*32+(lane>>4)*8 + 0..7] (8 bf16)
// ---------------------------------------------------------------------------
__global__ __launch_bounds__(256) void k_pre(
    const float* __restrict__ x, float* __restrict__ pooled,
    const float* __restrict__ w3, const float* __restrict__ b3,
    const float* __restrict__ gamma, const float* __restrict__ beta,
    const float* __restrict__ mean, const float* __restrict__ var,
    unsigned short* __restrict__ w3f, float* __restrict__ bias2)
{
    if (blockIdx.x < 2048) {
        int w    = threadIdx.x >> 6;
        int lane = threadIdx.x & 63;
        int row  = blockIdx.x * 4 + w;              // b*C + c
        const float4* xr = (const float4*)(x + (size_t)row * N);
        float s = 0.f;
        #pragma unroll
        for (int i = 0; i < 16; ++i) {
            float4 v = xr[i * 64 + lane];
            s += v.x + v.y + v.z + v.w;
        }
        #pragma unroll
        for (int off = 32; off; off >>= 1) s += __shfl_xor(s, off, 64);
        if (lane == 0) pooled[row] = s * (1.0f / N);
    } else {
        int idx  = (blockIdx.x - 2048) * 256 + threadIdx.x;  // 0..8191
        int g    = idx >> 6;          // fragment group 0..127
        int lane = idx & 63;
        int ck   = g >> 4;
        int kk   = (g >> 3) & 1;
        int ob   = g & 7;
        int o    = ob * 16 + (lane & 15);
        int c    = ck * 64 + kk * 32 + (lane >> 4) * 8;
        float inv = gamma[o] * rsqrtf(var[o] + 1e-5f);
        float4 a  = *(const float4*)(w3 + o * C + c);
        float4 bq = *(const float4*)(w3 + o * C + c + 4);
        unsigned r0 = f2bf(a.x * inv)  | (f2bf(a.y * inv) << 16);
        unsigned r1 = f2bf(a.z * inv)  | (f2bf(a.w * inv) << 16);
        unsigned r2 = f2bf(bq.x * inv) | (f2bf(bq.y * inv) << 16);
        unsigned r3 = f2bf(bq.z * inv) | (f2bf(bq.w * inv) << 16);
        *(uint4*)((char*)w3f + (size_t)idx * 16) = make_uint4(r0, r1, r2, r3);
        if (idx < CR) {
            float iv = gamma[idx] * rsqrtf(var[idx] + 1e-5f);
            bias2[idx] = b3[idx] * iv + beta[idx] - mean[idx] * iv;
        }
    }
}

// ---------------------------------------------------------------------------
// k_ca: channel-attention MLP.  One block (128 threads) per batch element.
// ---------------------------------------------------------------------------
__global__ __launch_bounds__(128) void k_ca(
    const float* __restrict__ pooled,
    const float* __restrict__ w1, const float* __restrict__ b1,
    const float* __restrict__ w2, const float* __restrict__ b2,
    float* __restrict__ ca)
{
    __shared__ float ps[C];
    __shared__ float hs[CR];
    int b = blockIdx.x, t = threadIdx.x;
    #pragma unroll
    for (int i = 0; i < 4; ++i) ps[t + i * 128] = pooled[b * C + t + i * 128];
    __syncthreads();

    float acc = b1[t];
    const float4* wr = (const float4*)(w1 + t * C);
    const float4* pr = (const float4*)ps;
    #pragma unroll 4
    for (int i = 0; i < C / 4; ++i) {
        float4 wv = wr[i], pv = pr[i];
        acc += wv.x * pv.x + wv.y * pv.y + wv.z * pv.z + wv.w * pv.w;
    }
    hs[t] = fmaxf(acc, 0.f);
    __syncthreads();

    #pragma unroll
    for (int k = 0; k < 4; ++k) {
        int c2 = t + k * 128;
        float a = b2[c2];
        const float4* w2r = (const float4*)(w2 + c2 * CR);
        const float4* hr  = (const float4*)hs;
        #pragma unroll 4
        for (int i = 0; i < CR / 4; ++i) {
            float4 wv = w2r[i], hv = hr[i];
            a += wv.x * hv.x + wv.y * hv.y + wv.z * hv.z + wv.w * hv.w;
        }
        ca[b * C + c2] = sigmoidf_(a);
    }
}

// ---------------------------------------------------------------------------
// k_wscale: per-batch fold of ca into the lane-ordered bf16 weights:
//   w3b[b][...] = bf16( fp32(w3f[...]) * ca[b][c(elem)] )
// Same fragment layout as w3f.  2 MB output, L2-resident for k_main.
// ---------------------------------------------------------------------------
__global__ __launch_bounds__(256) void k_wscale(
    const unsigned short* __restrict__ w3f, const float* __restrict__ ca,
    unsigned short* __restrict__ w3b)
{
    int idx  = blockIdx.x * 256 + threadIdx.x;   // 0 .. 16*8192-1
    int b    = idx >> 13;
    int i    = idx & 8191;
    int g    = i >> 6;
    int lane = i & 63;
    int ck   = g >> 4;
    int kk   = (g >> 3) & 1;
    int c0   = ck * 64 + kk * 32 + ((lane >> 4) << 3);
    uint4 wv = *(const uint4*)((const char*)w3f + (size_t)i * 16);
    const float* cb = ca + b * C + c0;
    float4 c01 = *(const float4*)cb;
    float4 c23 = *(const float4*)(cb + 4);
    uint4 ov;
    {
        float lo = __uint_as_float(wv.x << 16), hi = __uint_as_float(wv.x & 0xffff0000u);
        ov.x = f2bf(lo * c01.x) | (f2bf(hi * c01.y) << 16);
    }
    {
        float lo = __uint_as_float(wv.y << 16), hi = __uint_as_float(wv.y & 0xffff0000u);
        ov.y = f2bf(lo * c01.z) | (f2bf(hi * c01.w) << 16);
    }
    {
        float lo = __uint_as_float(wv.z << 16), hi = __uint_as_float(wv.z & 0xffff0000u);
        ov.z = f2bf(lo * c23.x) | (f2bf(hi * c23.y) << 16);
    }
    {
        float lo = __uint_as_float(wv.w << 16), hi = __uint_as_float(wv.w & 0xffff0000u);
        ov.w = f2bf(lo * c23.z) | (f2bf(hi * c23.w) << 16);
    }
    *(uint4*)((char*)w3b + (size_t)idx * 16) = ov;
}

// ---------------------------------------------------------------------------
// k_main (barrier-free K-loop): per (b, 64-col n-tile), 4 waves, each wave
// owns a 16-wide n-strip and ALL 128 o's:
//   h2[128][16] = w3b[b] @ x  over c=512 (ca pre-folded into w3b)
//   sa[n] = sigmoid(sum_o w4[o]*relu(h2+bias2) + b4);  out = x*(1+ca*sa)
// B-fragments gathered per-lane from x (8 stride-N dwords, 16-lane coalesced),
// 3-deep pipelined; A-fragments streamed from w3b (L2-hot).  NO LDS staging,
// NO K-loop barriers — waves drift freely, latency hidden by occupancy.
// ---------------------------------------------------------------------------
__global__ __launch_bounds__(256, 4) void k_main(
    const float* __restrict__ x, const float* __restrict__ ca,
    const unsigned short* __restrict__ w3b, const float* __restrict__ bias2,
    const float* __restrict__ w4, const float* __restrict__ b4,
    float* __restrict__ out)
{
    __shared__ float ca_s[C];
    __shared__ __align__(16) float sa_s[NT];
    __shared__ float bias2_s[CR];
    __shared__ float w4_s[CR];

    const int t    = threadIdx.x;
    const int lane = t & 63;
    const int w    = t >> 6;
    const int b    = blockIdx.y;
    const int n0   = blockIdx.x * NT;
    const int wn   = w * 16;

    ca_s[t]       = ca[b * C + t];
    ca_s[t + 256] = ca[b * C + t + 256];
    if (t < CR) { bias2_s[t] = bias2[t]; w4_s[t] = w4[t]; }

    const size_t xbase = (size_t)b * C * N + n0;
    // per-lane B column base: n = n0+wn+(lane&15), starting c = (lane>>4)*8
    const float* xcol = x + xbase + wn + (lane & 15) + (size_t)((lane >> 4) * 8) * N;
    const char*  wb   = (const char*)w3b + (size_t)b * (CR * C * 2);
    const int laneB   = lane * 16;

    f32x4 acc[8];
    #pragma unroll
    for (int i = 0; i < 8; ++i) acc[i] = (f32x4)0.f;

    float bst[3][8];

#define BLOAD(K16, S) do {                                      \
    _Pragma("unroll") for (int e = 0; e < 8; ++e)               \
        bst[S][e] = xcol[(size_t)((K16) * 32 + e) * N];         \
} while (0)

    BLOAD(0, 0);
    BLOAD(1, 1);

    #pragma unroll
    for (int k16 = 0; k16 < 16; ++k16) {
        // A fragments for this step (w3b is L2-hot, lane-pre-ordered)
        bf16x8 af[8];
        #pragma unroll
        for (int i = 0; i < 8; ++i)
            af[i] = *(const bf16x8*)(wb + (size_t)((k16 * 8 + i) * 64) * 16 + laneB);
        // keep the B pipeline 3 deep
        if (k16 < 14) BLOAD(k16 + 2, (k16 + 2) % 3);
        // convert current B chunk to bf16x8
        const int s = k16 % 3;
        union { u32x4 u; bf16x8 v; } bu;
        #pragma unroll
        for (int h = 0; h < 4; ++h)
            bu.u[h] = f2bf(bst[s][2 * h]) | (f2bf(bst[s][2 * h + 1]) << 16);
        #pragma unroll
        for (int i = 0; i < 8; ++i)
            acc[i] = __builtin_amdgcn_mfma_f32_16x16x32_bf16(af[i], bu.v, acc[i], 0, 0, 0);
    }
#undef BLOAD

    __syncthreads();    // bias2_s / w4_s / ca_s visibility

    // ---- sa: lane partial over its 32 o's; reduce across 16-lane groups.
    // acc[i] reg r = h2[o = i*16 + (lane>>4)*4 + r][n = wn + (lane&15)]
    float p = 0.f;
    #pragma unroll
    for (int i = 0; i < 8; ++i) {
        #pragma unroll
        for (int r = 0; r < 4; ++r) {
            int o = i * 16 + ((lane >> 4) << 2) + r;
            p = fmaf(w4_s[o], fmaxf(acc[i][r] + bias2_s[o], 0.f), p);
        }
    }
    p += __shfl_xor(p, 16, 64);
    p += __shfl_xor(p, 32, 64);
    if (lane < 16) sa_s[wn + lane] = sigmoidf_(p + b4[0]);
    __syncthreads();

    // ---- epilogue: out = x * (1 + ca[c]*sa[n]); x re-read is cache-hot
    #pragma unroll 4
    for (int it = 0; it < 32; ++it) {
        int f4 = it * 256 + t;          // 0..8191
        int c  = f4 >> 4;               // 0..511
        int n4 = f4 & 15;
        size_t off = xbase + (size_t)c * N + n4 * 4;
        float4 v = *(const float4*)(x + off);
        float cav = ca_s[c];
        float4 sv = *(const float4*)&sa_s[n4 * 4];
        float4 o4;
        o4.x = v.x * fmaf(cav, sv.x, 1.0f);
        o4.y = v.y * fmaf(cav, sv.y, 1.0f);
        o4.z = v.z * fmaf(cav, sv.z, 1.0f);
        o4.w = v.w * fmaf(cav, sv.w, 1.0f);
        *(float4*)(out + off) = o4;
    }
}

extern "C" void kernel_launch(void* const* d_in, const int* in_sizes, int n_in,
                              void* d_out, int out_size, void* d_ws, size_t ws_size,
                              hipStream_t stream)
{
    const float* x   = (const float*)d_in[0];
    const float* w1  = (const float*)d_in[1];
    const float* b1  = (const float*)d_in[2];
    const float* w2  = (const float*)d_in[3];
    const float* b2  = (const float*)d_in[4];
    const float* w3  = (const float*)d_in[5];
    const float* b3  = (const float*)d_in[6];
    const float* g   = (const float*)d_in[7];
    const float* be  = (const float*)d_in[8];
    const float* mn  = (const float*)d_in[9];
    const float* vr  = (const float*)d_in[10];
    const float* w4  = (const float*)d_in[11];
    const float* b4  = (const float*)d_in[12];
    float* out = (float*)d_out;

    float* ws     = (float*)d_ws;
    float* pooled = ws;                                  // 8192 floats
    float* ca     = ws + 8192;                           // 8192 floats
    float* bias2  = ws + 16384;                          // 128 floats (+pad)
    unsigned short* w3f = (unsigned short*)(ws + 16640); // 65536 bf16 (128 KB)
    unsigned short* w3b = (unsigned short*)(ws + 16640 + 32768); // 16*65536 bf16 (2 MB)

    k_pre<<<2048 + 32, 256, 0, stream>>>(x, pooled, w3, b3, g, be, mn, vr, w3f, bias2);
    k_ca<<<B, 128, 0, stream>>>(pooled, w1, b1, w2, b2, ca);
    k_wscale<<<B * 8192 / 256, 256, 0, stream>>>(w3f, ca, w3b);
    dim3 g3(N / NT, B);
    k_main<<<g3, 256, 0, stream>>>(x, ca, w3b, bias2, w4, b4, out);
}

// Round 8
// 121.235 us; speedup vs baseline: 1.1065x; 1.1065x over previous
//
#include <hip/hip_runtime.h>
#include <math.h>

// Shapes fixed by the reference: x [B=16, C=512, N=4096] fp32.
constexpr int B  = 16;
constexpr int C  = 512;
constexpr int N  = 4096;
constexpr int CR = 128;   // C/4
constexpr int NT = 128;   // n-tile per k_main block (512B row segments)
constexpr int KC = 64;    // c-chunk per staging step

typedef __attribute__((ext_vector_type(8))) short bf16x8;
typedef __attribute__((ext_vector_type(4))) float f32x4;

__device__ __forceinline__ float sigmoidf_(float v) {
    return 1.0f / (1.0f + __expf(-v));
}
// fp32 -> bf16 round-to-nearest-even
__device__ __forceinline__ unsigned f2bf(float f) {
    unsigned u = __float_as_uint(f);
    u += 0x7fffu + ((u >> 16) & 1u);
    return u >> 16;
}

// lgkmcnt(0) + raw barrier: LDS writes visible WITHOUT draining vmcnt,
// so in-flight global prefetches survive the barrier (anti-m97-stall).
#define LGKM_BARRIER() do {                                   \
    asm volatile("s_waitcnt lgkmcnt(0)" ::: "memory");        \
    __builtin_amdgcn_s_barrier();                             \
    asm volatile("" ::: "memory");                            \
} while (0)

// ---------------------------------------------------------------------------
// k_pre: fused  (blocks 0..2047)  pooled[b][c] = mean_n x[b][c][n]
//               (blocks 2048..2079) BN-fold w3 -> bf16 in MFMA A-FRAGMENT
//               lane order (w3f) + bias2.
// w3f layout: group g = ck*16 + kk*8 + ob ; byte(g,lane) = (g*64+lane)*16
//   content: w[ob*16+(lane&15)][ck*64+kk*32+(lane>>4)*8 + 0..7] (8 bf16)
// ---------------------------------------------------------------------------
__global__ __launch_bounds__(256) void k_pre(
    const float* __restrict__ x, float* __restrict__ pooled,
    const float* __restrict__ w3, const float* __restrict__ b3,
    const float* __restrict__ gamma, const float* __restrict__ beta,
    const float* __restrict__ mean, const float* __restrict__ var,
    unsigned short* __restrict__ w3f, float* __restrict__ bias2)
{
    if (blockIdx.x < 2048) {
        int w    = threadIdx.x >> 6;
        int lane = threadIdx.x & 63;
        int row  = blockIdx.x * 4 + w;              // b*C + c
        const float4* xr = (const float4*)(x + (size_t)row * N);
        float s = 0.f;
        #pragma unroll
        for (int i = 0; i < 16; ++i) {
            float4 v = xr[i * 64 + lane];
            s += v.x + v.y + v.z + v.w;
        }
        #pragma unroll
        for (int off = 32; off; off >>= 1) s += __shfl_xor(s, off, 64);
        if (lane == 0) pooled[row] = s * (1.0f / N);
    } else {
        int idx  = (blockIdx.x - 2048) * 256 + threadIdx.x;  // 0..8191
        int g    = idx >> 6;          // fragment group 0..127
        int lane = idx & 63;
        int ck   = g >> 4;
        int kk   = (g >> 3) & 1;
        int ob   = g & 7;
        int o    = ob * 16 + (lane & 15);
        int c    = ck * 64 + kk * 32 + (lane >> 4) * 8;
        float inv = gamma[o] * rsqrtf(var[o] + 1e-5f);
        float4 a  = *(const float4*)(w3 + o * C + c);
        float4 bq = *(const float4*)(w3 + o * C + c + 4);
        unsigned r0 = f2bf(a.x * inv)  | (f2bf(a.y * inv) << 16);
        unsigned r1 = f2bf(a.z * inv)  | (f2bf(a.w * inv) << 16);
        unsigned r2 = f2bf(bq.x * inv) | (f2bf(bq.y * inv) << 16);
        unsigned r3 = f2bf(bq.z * inv) | (f2bf(bq.w * inv) << 16);
        *(uint4*)((char*)w3f + (size_t)idx * 16) = make_uint4(r0, r1, r2, r3);
        if (idx < CR) {
            float iv = gamma[idx] * rsqrtf(var[idx] + 1e-5f);
            bias2[idx] = b3[idx] * iv + beta[idx] - mean[idx] * iv;
        }
    }
}

// ---------------------------------------------------------------------------
// k_ca: channel-attention MLP.  One block (128 threads) per batch element.
// ---------------------------------------------------------------------------
__global__ __launch_bounds__(128) void k_ca(
    const float* __restrict__ pooled,
    const float* __restrict__ w1, const float* __restrict__ b1,
    const float* __restrict__ w2, const float* __restrict__ b2,
    float* __restrict__ ca)
{
    __shared__ float ps[C];
    __shared__ float hs[CR];
    int b = blockIdx.x, t = threadIdx.x;
    #pragma unroll
    for (int i = 0; i < 4; ++i) ps[t + i * 128] = pooled[b * C + t + i * 128];
    __syncthreads();

    float acc = b1[t];
    const float4* wr = (const float4*)(w1 + t * C);
    const float4* pr = (const float4*)ps;
    #pragma unroll 4
    for (int i = 0; i < C / 4; ++i) {
        float4 wv = wr[i], pv = pr[i];
        acc += wv.x * pv.x + wv.y * pv.y + wv.z * pv.z + wv.w * pv.w;
    }
    hs[t] = fmaxf(acc, 0.f);
    __syncthreads();

    #pragma unroll
    for (int k = 0; k < 4; ++k) {
        int c2 = t + k * 128;
        float a = b2[c2];
        const float4* w2r = (const float4*)(w2 + c2 * CR);
        const float4* hr  = (const float4*)hs;
        #pragma unroll 4
        for (int i = 0; i < CR / 4; ++i) {
            float4 wv = w2r[i], hv = hr[i];
            a += wv.x * hv.x + wv.y * hv.y + wv.z * hv.z + wv.w * hv.w;
        }
        ca[b * C + c2] = sigmoidf_(a);
    }
}

// ---------------------------------------------------------------------------
// k_main: per (b, 128-col n-tile), 512 threads / 8 waves:
//   h2[128 o][128 n] = W @ (x*ca) over c=512 via mfma_f32_16x16x32_bf16
//   sa[n] = sigmoid(sum_o w4[o]*relu(h2+bias2) + b4);  out = x*(1+ca*sa)
// Wave w: o-strip (w&3)*32 (2 frags), n-strip (w>>2)*64 (4 frags).
// x staged via 2-deep reg prefetch -> bf16*ca -> swizzled LDS dbuf;
// A-frags direct from global w3f (128 KB, L2-hot, lane-pre-ordered);
// one lgkm-only barrier per chunk (vmcnt never drained in-loop).
// ---------------------------------------------------------------------------
__global__ __launch_bounds__(512, 2) void k_main(
    const float* __restrict__ x, const float* __restrict__ ca,
    const unsigned short* __restrict__ w3f, const float* __restrict__ bias2,
    const float* __restrict__ w4, const float* __restrict__ b4,
    float* __restrict__ out)
{
    __shared__ __align__(16) short lds_x[2][NT * KC];   // 2 x 16 KB, swizzled [n][c]
    __shared__ float ca_s[C];
    __shared__ __align__(16) float sa_s[NT];
    __shared__ float red[4][NT];
    __shared__ float bias2_s[CR];
    __shared__ float w4_s[CR];

    const int t    = threadIdx.x;
    const int lane = t & 63;
    const int w    = t >> 6;           // 0..7
    const int b    = blockIdx.y;
    const int n0   = blockIdx.x * NT;
    const int wo   = (w & 3) * 32;     // wave o-base (4 o-strips)
    const int wn   = (w >> 2) * 64;    // wave n-base (2 n-strips)
    const int ob0  = (w & 3) * 2;

    const size_t xbase = (size_t)b * C * N + n0;
    const int ng = t & 63;   // x-stage: n pair = 2*ng  (128 n)
    const int cg = t >> 6;   // x-stage: c sub  = cg*8  (8 rows/thread)

    float2 xva[8], xvb[8];

#define LOADX(dst, CK) do { const int c0_ = (CK) * KC;                         \
    _Pragma("unroll") for (int ci = 0; ci < 8; ++ci)                           \
        dst[ci] = *(const float2*)(x + xbase + (size_t)(c0_ + cg * 8 + ci) * N + 2 * ng); \
} while (0)

#define CONVERT_WRITE(src, CK, BUF) do { const int c0_ = (CK) * KC;            \
    unsigned q0[4], q1[4];                                                     \
    _Pragma("unroll") for (int h = 0; h < 4; ++h) {                            \
        float s0 = ca_s[c0_ + cg * 8 + 2 * h];                                 \
        float s1 = ca_s[c0_ + cg * 8 + 2 * h + 1];                             \
        q0[h] = f2bf(src[2 * h].x * s0) | (f2bf(src[2 * h + 1].x * s1) << 16); \
        q1[h] = f2bf(src[2 * h].y * s0) | (f2bf(src[2 * h + 1].y * s1) << 16); \
    }                                                                          \
    int nl0 = 2 * ng, nl1 = 2 * ng + 1;                                        \
    int a0 = (nl0 * 128 + cg * 16) ^ ((nl0 & 7) << 4);                         \
    int a1 = (nl1 * 128 + cg * 16) ^ ((nl1 & 7) << 4);                         \
    *(uint4*)((char*)lds_x[BUF] + a0) = make_uint4(q0[0], q0[1], q0[2], q0[3]);\
    *(uint4*)((char*)lds_x[BUF] + a1) = make_uint4(q1[0], q1[1], q1[2], q1[3]);\
} while (0)

    // prologue: first two x chunks in flight immediately
    LOADX(xva, 0);
    LOADX(xvb, 1);

    ca_s[t] = ca[b * C + t];
    if (t < CR) { bias2_s[t] = bias2[t]; w4_s[t] = w4[t]; }
    LGKM_BARRIER();                 // ca_s visible (vmcnt NOT drained)

    CONVERT_WRITE(xva, 0, 0);       // chunk 0 -> buf 0

    f32x4 acc[2][4];
    #pragma unroll
    for (int i = 0; i < 2; ++i)
        #pragma unroll
        for (int j = 0; j < 4; ++j) acc[i][j] = (f32x4)0.f;

    const char* wf = (const char*)w3f;

    #pragma unroll
    for (int ck = 0; ck < 8; ++ck) {
        // prefetch x chunk ck+2 into the set freed one iteration ago
        if (ck < 6) { if (ck & 1) LOADX(xvb, ck + 2); else LOADX(xva, ck + 2); }

        LGKM_BARRIER();             // buf(ck&1) visible to all waves

        #pragma unroll
        for (int kk = 0; kk < 2; ++kk) {
            // A-fragments direct from global (128 KB shared, L2-hot)
            bf16x8 af[2];
            #pragma unroll
            for (int i = 0; i < 2; ++i) {
                int g = ck * 16 + kk * 8 + ob0 + i;
                af[i] = *(const bf16x8*)(wf + (size_t)(g * 64 + lane) * 16);
            }
            bf16x8 bfr[4];
            #pragma unroll
            for (int j = 0; j < 4; ++j) {
                int br = wn + j * 16 + (lane & 15);
                int bb = (br * 128 + kk * 64 + (lane >> 4) * 16) ^ ((br & 7) << 4);
                bfr[j] = *(const bf16x8*)((const char*)lds_x[ck & 1] + bb);
            }
            #pragma unroll
            for (int i = 0; i < 2; ++i)
                #pragma unroll
                for (int j = 0; j < 4; ++j)
                    acc[i][j] = __builtin_amdgcn_mfma_f32_16x16x32_bf16(af[i], bfr[j], acc[i][j], 0, 0, 0);
        }
        // convert chunk ck+1 (loaded last iteration) into the other buffer
        if (ck < 7) { if (ck & 1) CONVERT_WRITE(xva, ck + 1, 0); else CONVERT_WRITE(xvb, ck + 1, 1); }
    }

    // ---- sa: per-lane partial over this wave's 32 o's, then cross-lane.
    // C/D layout: col = lane&15 (n), row = (lane>>4)*4 + reg (o)
    #pragma unroll
    for (int j = 0; j < 4; ++j) {
        float p = 0.f;
        #pragma unroll
        for (int i = 0; i < 2; ++i) {
            #pragma unroll
            for (int r = 0; r < 4; ++r) {
                int o = wo + i * 16 + ((lane >> 4) << 2) + r;
                p = fmaf(w4_s[o], fmaxf(acc[i][j][r] + bias2_s[o], 0.f), p);
            }
        }
        p += __shfl_xor(p, 16, 64);
        p += __shfl_xor(p, 32, 64);
        if (lane < 16) red[w & 3][wn + j * 16 + lane] = p;
    }
    __syncthreads();
    if (t < NT) sa_s[t] = sigmoidf_(red[0][t] + red[1][t] + red[2][t] + red[3][t] + b4[0]);
    __syncthreads();

    // ---- epilogue: out = x * (1 + ca[c]*sa[n]); 512B per row segment
    #pragma unroll 4
    for (int it = 0; it < 32; ++it) {
        int f4 = it * 512 + t;          // 0..16383
        int c  = f4 >> 5;               // 0..511
        int n4 = f4 & 31;
        size_t off = xbase + (size_t)c * N + n4 * 4;
        float4 v = *(const float4*)(x + off);
        float cav = ca_s[c];
        float4 sv = *(const float4*)&sa_s[n4 * 4];
        float4 o4;
        o4.x = v.x * fmaf(cav, sv.x, 1.0f);
        o4.y = v.y * fmaf(cav, sv.y, 1.0f);
        o4.z = v.z * fmaf(cav, sv.z, 1.0f);
        o4.w = v.w * fmaf(cav, sv.w, 1.0f);
        *(float4*)(out + off) = o4;
    }
#undef LOADX
#undef CONVERT_WRITE
}

extern "C" void kernel_launch(void* const* d_in, const int* in_sizes, int n_in,
                              void* d_out, int out_size, void* d_ws, size_t ws_size,
                              hipStream_t stream)
{
    const float* x   = (const float*)d_in[0];
    const float* w1  = (const float*)d_in[1];
    const float* b1  = (const float*)d_in[2];
    const float* w2  = (const float*)d_in[3];
    const float* b2  = (const float*)d_in[4];
    const float* w3  = (const float*)d_in[5];
    const float* b3  = (const float*)d_in[6];
    const float* g   = (const float*)d_in[7];
    const float* be  = (const float*)d_in[8];
    const float* mn  = (const float*)d_in[9];
    const float* vr  = (const float*)d_in[10];
    const float* w4  = (const float*)d_in[11];
    const float* b4  = (const float*)d_in[12];
    float* out = (float*)d_out;

    float* ws     = (float*)d_ws;
    float* pooled = ws;                                  // 8192 floats
    float* ca     = ws + 8192;                           // 8192 floats
    float* bias2  = ws + 16384;                          // 128 floats (+pad)
    unsigned short* w3f = (unsigned short*)(ws + 16640); // 65536 bf16 (128 KB)

    k_pre<<<2048 + 32, 256, 0, stream>>>(x, pooled, w3, b3, g, be, mn, vr, w3f, bias2);
    k_ca<<<B, 128, 0, stream>>>(pooled, w1, b1, w2, b2, ca);
    dim3 g3(N / NT, B);
    k_main<<<g3, 512, 0, stream>>>(x, ca, w3f, bias2, w4, b4, out);
}